// Round 16
// baseline (113.054 us; speedup 1.0000x reference)
//
#include <hip/hip_runtime.h>

// Problem constants (match reference)
#define NB 32
#define CH 3
#define HH 768
#define WW 768

// No-LDS direct-from-L1 conv: each lane owns an aligned float4 granule,
// halo via DPP cross-lane (VALU pipe), zero LDS / zero barriers.
#define TW 64
#define TH 32
#define TPB 4
#define NTC (WW / TW)           // 12
#define NTG (HH / (TH * TPB))   // 6
#define NWG (NB * NTC * NTG)    // 2304, %8==0
#define RY 2

typedef float v4f __attribute__((ext_vector_type(4)));

template <bool B> struct BoolC { static constexpr bool value = B; };

// DPP within 16-lane rows (tx groups align exactly with DPP rows).
// row_shr:1 (0x111): lane i <- lane i-1 ; row_shl:1 (0x101): lane i <- lane i+1.
// bound_ctrl=1 -> out-of-row reads 0 (patched below for tx==0 / tx==15).
__device__ __forceinline__ float dpp_from_lower(float x) {   // lane i <- i-1
    return __int_as_float(__builtin_amdgcn_update_dpp(
        0, __float_as_int(x), 0x111, 0xF, 0xF, true));
}
__device__ __forceinline__ float dpp_from_higher(float x) {  // lane i <- i+1
    return __int_as_float(__builtin_amdgcn_update_dpp(
        0, __float_as_int(x), 0x101, 0xF, 0xF, true));
}

__global__ __launch_bounds__(256) void colwarp_conv_kernel(
    const float* __restrict__ im,
    const float* __restrict__ flat,
    float* __restrict__ out)
{
    // XCD-contiguous mapping; one XCD owns whole images (4 each).
    const int d   = blockIdx.x;
    const int wid = (d & 7) * (NWG / 8) + (d >> 3);
    const int tc  = wid % NTC;
    const int t2  = wid / NTC;
    const int tg  = t2 % NTG;
    const int b   = t2 / NTG;
    const int tw0 = tc * TW;
    const int thbase = tg * (TPB * TH);

    // ---- per-sample params (b block-uniform -> scalar) ----
    const float* f = flat + b * 37;
    float Wm[3][3];
#pragma unroll
    for (int i = 0; i < 3; ++i)
#pragma unroll
        for (int j = 0; j < 3; ++j) Wm[i][j] = f[i * 3 + j];
    float sh3[3];
#pragma unroll
    for (int i = 0; i < 3; ++i) sh3[i] = f[9 + i];
    float K[5][5];
    float sumK = 0.f;
#pragma unroll
    for (int i = 0; i < 5; ++i)
#pragma unroll
        for (int j = 0; j < 5; ++j) { K[i][j] = f[12 + i * 5 + j]; sumK += K[i][j]; }
    // interior shift contribution: out_c += sumK * (sh . Wm[:,c])
    float sb[3];
#pragma unroll
    for (int c = 0; c < 3; ++c)
        sb[c] = sumK * (sh3[0]*Wm[0][c] + sh3[1]*Wm[1][c] + sh3[2]*Wm[2][c]);

    const size_t plane = (size_t)HH * WW;
    const float* cbase = im + (size_t)b * CH * plane;
    const float* cb[3] = {cbase, cbase + plane, cbase + 2 * plane};
    float* obase = out + (size_t)b * CH * plane;
    float* ob[3] = {obase, obase + plane, obase + 2 * plane};

    const int tx = threadIdx.x & 15;   // own granule: cols tw0+4tx .. +3
    const int ty = threadIdx.x >> 4;   // 0..15, 2 output rows each
    const int xo = tw0 + 4 * tx;

    // DPP row-boundary patch source: tx==0 needs cols tw0-2,-1 ; tx==15 needs
    // cols tw0+64,+65. One float2 load covers it (other lanes load harmlessly).
    const int ecol_raw = (tx == 0) ? (tw0 - 2) : (tw0 + TW);
    const bool eok = (ecol_raw >= 0) && (ecol_raw + 1 < WW);
    const int ecol = eok ? ecol_raw : 0;

    auto conv_tile = [&](int th0, auto gc) {
        constexpr bool GUARD = decltype(gc)::value;
        float acc[CH][RY][4];
#pragma unroll
        for (int c = 0; c < CH; ++c)
#pragma unroll
            for (int r = 0; r < RY; ++r)
#pragma unroll
                for (int o = 0; o < 4; ++o) acc[c][r][o] = 0.f;

        const int rb = th0 + RY * ty - 2;   // input row for rr=0
#pragma unroll
        for (int rr = 0; rr < RY + 4; ++rr) {
            int gh = rb + rr;
            bool rowok = true;
            if (GUARD) {
                rowok = ((unsigned)gh < (unsigned)HH);
                gh = gh < 0 ? 0 : (gh > HH - 1 ? HH - 1 : gh);
            }
            const size_t roff = (size_t)gh * WW;
#pragma unroll
            for (int c = 0; c < CH; ++c) {
                const float* rp = cb[c] + roff;
                const float4 own = *(const float4*)(rp + xo);
                const float2 ev  = *(const float2*)(rp + ecol);
                float l2 = dpp_from_lower(own.z);    // col 4tx-2
                float l3 = dpp_from_lower(own.w);    // col 4tx-1
                float r4 = dpp_from_higher(own.x);   // col 4tx+4
                float r5 = dpp_from_higher(own.y);   // col 4tx+5
                const float e0 = eok ? ev.x : 0.f;
                const float e1 = eok ? ev.y : 0.f;
                if (tx == 0)  { l2 = e0; l3 = e1; }
                if (tx == 15) { r4 = e0; r5 = e1; }
                float w8[8] = {l2, l3, own.x, own.y, own.z, own.w, r4, r5};
                if (GUARD) {
                    const float s = sh3[c];
                    const bool lv = (tx != 0)  || eok;   // left-patch col valid
                    const bool rv = (tx != 15) || eok;   // right-patch col valid
                    w8[0] = (rowok && lv) ? w8[0] + s : 0.f;
                    w8[1] = (rowok && lv) ? w8[1] + s : 0.f;
                    w8[2] = rowok ? w8[2] + s : 0.f;
                    w8[3] = rowok ? w8[3] + s : 0.f;
                    w8[4] = rowok ? w8[4] + s : 0.f;
                    w8[5] = rowok ? w8[5] + s : 0.f;
                    w8[6] = (rowok && rv) ? w8[6] + s : 0.f;
                    w8[7] = (rowok && rv) ? w8[7] + s : 0.f;
                }
#pragma unroll
                for (int i = 0; i < 5; ++i) {
                    const int r = rr - i;
                    if (r >= 0 && r < RY) {
#pragma unroll
                        for (int j = 0; j < 5; ++j) {
#pragma unroll
                            for (int o = 0; o < 4; ++o)
                                acc[c][r][o] += w8[o + j] * K[i][j];
                        }
                    }
                }
            }
        }

        // epilogue: 3x3 mix (+ interior shift term), NT float4 stores
#pragma unroll
        for (int c = 0; c < CH; ++c) {
#pragma unroll
            for (int r = 0; r < RY; ++r) {
                v4f vv;
#pragma unroll
                for (int o = 0; o < 4; ++o) {
                    float v = acc[0][r][o]*Wm[0][c] + acc[1][r][o]*Wm[1][c]
                            + acc[2][r][o]*Wm[2][c];
                    if (!GUARD) v += sb[c];
                    vv[o] = v;
                }
                __builtin_nontemporal_store(vv,
                    (v4f*)&ob[c][(size_t)(th0 + RY * ty + r) * WW + xo]);
            }
        }
    };

#pragma unroll 1
    for (int t = 0; t < TPB; ++t) {
        const int th0 = thbase + t * TH;
        const bool guard = (tc == 0) || (tc == NTC - 1) ||
                           (th0 == 0) || (th0 == HH - TH);
        if (guard) conv_tile(th0, BoolC<true>{});
        else       conv_tile(th0, BoolC<false>{});
    }
}

extern "C" void kernel_launch(void* const* d_in, const int* in_sizes, int n_in,
                              void* d_out, int out_size, void* d_ws, size_t ws_size,
                              hipStream_t stream) {
    const float* im   = (const float*)d_in[0];
    const float* flat = (const float*)d_in[1];
    float* out        = (float*)d_out;

    colwarp_conv_kernel<<<dim3(NWG), dim3(256), 0, stream>>>(im, flat, out);
}

// Round 17
// 102.306 us; speedup vs baseline: 1.1050x; 1.1050x over previous
//
#include <hip/hip_runtime.h>

#define NB 32
#define CH 3
#define HH 768
#define WW 768

// Rolling-accumulator vertical streaming, zero LDS / zero barriers.
// Thread = 4 cols x 8 output rows; streams 12 input rows; halo via DPP.
#define TW 64
#define RB 128                  // rows per block band (16 ty x 8)
#define RT 8                    // output rows per thread
#define NTC (WW / TW)           // 12
#define NVB (HH / RB)           // 6
#define NWG (NB * NTC * NVB)    // 2304, %8==0

typedef float v4f __attribute__((ext_vector_type(4)));

template <bool B> struct BoolC { static constexpr bool value = B; };

// DPP within 16-lane rows (tx groups align exactly with DPP rows).
__device__ __forceinline__ float dpp_from_lower(float x) {   // lane i <- i-1
    return __int_as_float(__builtin_amdgcn_update_dpp(
        0, __float_as_int(x), 0x111, 0xF, 0xF, true));
}
__device__ __forceinline__ float dpp_from_higher(float x) {  // lane i <- i+1
    return __int_as_float(__builtin_amdgcn_update_dpp(
        0, __float_as_int(x), 0x101, 0xF, 0xF, true));
}

// Complete band-local output row (KK-4): 3x3 mix + NT store, zero the slot.
#define COMPLETE(KK)                                                           \
  {                                                                            \
    const int orow = r0 + (KK) - 4;                                            \
    _Pragma("unroll")                                                          \
    for (int c = 0; c < CH; ++c) {                                             \
      v4f vv;                                                                  \
      _Pragma("unroll")                                                        \
      for (int o = 0; o < 4; ++o)                                              \
        vv[o] = acc[((KK) - 4) % 5][0][o] * Wm[0][c]                           \
              + acc[((KK) - 4) % 5][1][o] * Wm[1][c]                           \
              + acc[((KK) - 4) % 5][2][o] * Wm[2][c];                          \
      __builtin_nontemporal_store(vv,                                          \
          (v4f*)&ob[c][(size_t)orow * WW + xo]);                               \
    }                                                                          \
    _Pragma("unroll")                                                          \
    for (int cz = 0; cz < CH; ++cz)                                            \
      _Pragma("unroll")                                                        \
      for (int oz = 0; oz < 4; ++oz) acc[((KK) - 4) % 5][cz][oz] = 0.f;        \
  }

// Process input row k=KK (global row r0-2+KK). Taps i in [IMIN,IMAX] feed
// output rows o = KK-i (slot o%5). All acc indices compile-time constant.
#define DO_ROW(KK, IMIN, IMAX, DOCOMP)                                         \
  {                                                                            \
    const int g = r0 - 2 + (KK);                                               \
    const bool rowok = ((unsigned)g < (unsigned)HH);                           \
    const int gcl = g < 0 ? 0 : (g > HH - 1 ? HH - 1 : g);                     \
    const size_t roff = (size_t)gcl * WW;                                      \
    float w8[CH][8];                                                           \
    _Pragma("unroll")                                                          \
    for (int c = 0; c < CH; ++c) {                                             \
      const float* rp = cb[c] + roff;                                          \
      const float4 own = *(const float4*)(rp + xo);                            \
      const float2 ev  = *(const float2*)(rp + ecol);                          \
      float l2 = dpp_from_lower(own.z);                                        \
      float l3 = dpp_from_lower(own.w);                                        \
      float r4 = dpp_from_higher(own.x);                                       \
      float r5 = dpp_from_higher(own.y);                                       \
      if (tx == 0)  { l2 = ev.x; l3 = ev.y; }                                  \
      if (tx == 15) { r4 = ev.x; r5 = ev.y; }                                  \
      const float s = sh3[c];                                                  \
      const bool lv = !GUARD || (tx != 0)  || eok;                             \
      const bool rv = !GUARD || (tx != 15) || eok;                             \
      w8[c][0] = (rowok && lv) ? l2 + s    : 0.f;                              \
      w8[c][1] = (rowok && lv) ? l3 + s    : 0.f;                              \
      w8[c][2] = rowok         ? own.x + s : 0.f;                              \
      w8[c][3] = rowok         ? own.y + s : 0.f;                              \
      w8[c][4] = rowok         ? own.z + s : 0.f;                              \
      w8[c][5] = rowok         ? own.w + s : 0.f;                              \
      w8[c][6] = (rowok && rv) ? r4 + s    : 0.f;                              \
      w8[c][7] = (rowok && rv) ? r5 + s    : 0.f;                              \
    }                                                                          \
    _Pragma("unroll")                                                          \
    for (int i = (IMIN); i <= (IMAX); ++i) {                                   \
      _Pragma("unroll")                                                        \
      for (int c = 0; c < CH; ++c) {                                           \
        _Pragma("unroll")                                                      \
        for (int j = 0; j < 5; ++j) {                                          \
          _Pragma("unroll")                                                    \
          for (int o = 0; o < 4; ++o)                                          \
            acc[((KK) - i) % 5][c][o] += w8[c][o + j] * Kf[i][j];              \
        }                                                                      \
      }                                                                        \
    }                                                                          \
    if (DOCOMP) COMPLETE(KK);                                                  \
  }

__global__ __launch_bounds__(256) void colwarp_conv_kernel(
    const float* __restrict__ im,
    const float* __restrict__ flat,
    float* __restrict__ out)
{
    // XCD-contiguous mapping; one XCD owns whole images (4 each).
    const int d   = blockIdx.x;
    const int wid = (d & 7) * (NWG / 8) + (d >> 3);
    const int tc  = wid % NTC;
    const int t2  = wid / NTC;
    const int vb  = t2 % NVB;
    const int b   = t2 / NVB;
    const int tw0 = tc * TW;

    const int tx = threadIdx.x & 15;   // own granule: cols tw0+4tx..+3
    const int ty = threadIdx.x >> 4;   // 0..15: 8 output rows each
    const int r0 = vb * RB + ty * RT;  // first output row of this thread
    const int xo = tw0 + 4 * tx;

    // ---- per-sample params (b block-uniform -> scalar) ----
    const float* f = flat + b * 37;
    float Wm[3][3];
#pragma unroll
    for (int i = 0; i < 3; ++i)
#pragma unroll
        for (int j = 0; j < 3; ++j) Wm[i][j] = f[i * 3 + j];
    float sh3[3];
#pragma unroll
    for (int i = 0; i < 3; ++i) sh3[i] = f[9 + i];
    float Kf[5][5];
#pragma unroll
    for (int i = 0; i < 5; ++i)
#pragma unroll
        for (int j = 0; j < 5; ++j) Kf[i][j] = f[12 + i * 5 + j];

    const size_t plane = (size_t)HH * WW;
    const float* cbase = im + (size_t)b * CH * plane;
    const float* cb[3] = {cbase, cbase + plane, cbase + 2 * plane};
    float* obase = out + (size_t)b * CH * plane;
    float* ob[3] = {obase, obase + plane, obase + 2 * plane};

    // Edge-patch source (2 floats just outside the wave's 64-col granule set).
    const int ecol_raw = (tx == 0) ? (tw0 - 2) : (tw0 + TW);
    const bool eok = (ecol_raw >= 0) && (ecol_raw + 1 < WW);
    const int ecol = eok ? ecol_raw : 0;

    // Rolling accumulators: 5 in-flight output rows x 3 ch x 4 cols.
    float acc[5][CH][4];
#pragma unroll
    for (int s = 0; s < 5; ++s)
#pragma unroll
        for (int c = 0; c < CH; ++c)
#pragma unroll
            for (int o = 0; o < 4; ++o) acc[s][c][o] = 0.f;

    auto body = [&](auto gc) {
        constexpr bool GUARD = decltype(gc)::value;
        DO_ROW(0,  0, 0, false);
        DO_ROW(1,  0, 1, false);
        DO_ROW(2,  0, 2, false);
        DO_ROW(3,  0, 3, false);
        DO_ROW(4,  0, 4, true);   // completes o=0
        DO_ROW(5,  0, 4, true);
        DO_ROW(6,  0, 4, true);
        DO_ROW(7,  0, 4, true);
        DO_ROW(8,  1, 4, true);
        DO_ROW(9,  2, 4, true);
        DO_ROW(10, 3, 4, true);
        DO_ROW(11, 4, 4, true);   // completes o=7
    };

    if (tc == 0 || tc == NTC - 1) body(BoolC<true>{});
    else                          body(BoolC<false>{});
}

extern "C" void kernel_launch(void* const* d_in, const int* in_sizes, int n_in,
                              void* d_out, int out_size, void* d_ws, size_t ws_size,
                              hipStream_t stream) {
    const float* im   = (const float*)d_in[0];
    const float* flat = (const float*)d_in[1];
    float* out        = (float*)d_out;

    colwarp_conv_kernel<<<dim3(NWG), dim3(256), 0, stream>>>(im, flat, out);
}